// Round 1
// baseline (1845.068 us; speedup 1.0000x reference)
//
#include <hip/hip_runtime.h>

// Sparse ConvTranspose3d scatter-GEMM for MI355X (gfx950).
// feats: (N, 64) f32; weight: (27, 64, 64) f32; bias: (64,) f32;
// out_index: (27, N) i32; out: (N*27, 64) f32.
// out[r] = bias + sum_{(k,n): idx[k][n]==r} feats[n] @ weight[k]^T

constexpr int NPTS   = 60000;
constexpr int CIN_   = 64;
constexpr int COUT_  = 64;
constexpr int KV_    = 27;
constexpr long NOUT  = (long)NPTS * KV_;          // 1,620,000 output rows
constexpr int CH     = 128;                       // points per wave
constexpr int NCHUNK = (NPTS + CH - 1) / CH;      // 469
constexpr int NWAVES = KV_ * NCHUNK;              // 12,663

// ---------------------------------------------------------------------------
// Kernel 1: out[row][c] = bias[c] for every row (poisoned buffer -> must init).
// Pure write stream, float4 stores, grid-stride.
// ---------------------------------------------------------------------------
__global__ __launch_bounds__(256) void bias_init_kernel(const float* __restrict__ bias,
                                                        float* __restrict__ out) {
    __shared__ float4 b4[16];
    if (threadIdx.x < 16) b4[threadIdx.x] = reinterpret_cast<const float4*>(bias)[threadIdx.x];
    __syncthreads();
    const long total4 = NOUT * (COUT_ / 4);       // 25,920,000 float4s
    long i = (long)blockIdx.x * blockDim.x + threadIdx.x;
    const long stride = (long)gridDim.x * blockDim.x;
    float4* out4 = reinterpret_cast<float4*>(out);
    for (; i < total4; i += stride) {
        out4[i] = b4[i & 15];
    }
}

// ---------------------------------------------------------------------------
// Kernel 2: each wave owns (k, chunk of CH points).
//   - weight[k][lane][0..63] cached in 16 float4 VGPRs, reused for CH points
//   - feats row read as wave-uniform broadcast float4 loads (L2/L3 resident)
//   - lane c computes dot(feats[n], weight[k][c]) then 64-lane contiguous
//     256B atomicAdd into out[idx*64 + c]
// ---------------------------------------------------------------------------
__global__ __launch_bounds__(256) void scatter_gemm_kernel(const float* __restrict__ feats,
                                                           const float* __restrict__ weight,
                                                           const int* __restrict__ out_index,
                                                           float* __restrict__ out) {
    const int wave = (blockIdx.x << 2) | (threadIdx.x >> 6);
    if (wave >= NWAVES) return;
    const int lane  = threadIdx.x & 63;
    const int k     = wave / NCHUNK;              // block's 4 waves share k mostly
    const int chunk = wave - k * NCHUNK;
    const int n0 = chunk * CH;
    const int n1 = (n0 + CH < NPTS) ? (n0 + CH) : NPTS;

    // 64 VGPRs of weight, loaded once per wave
    const float4* wrow = reinterpret_cast<const float4*>(
        weight + ((size_t)k * COUT_ + lane) * CIN_);
    float4 w[16];
#pragma unroll
    for (int q = 0; q < 16; ++q) w[q] = wrow[q];

    const int* __restrict__ idxp = out_index + (size_t)k * NPTS;

    for (int n = n0; n < n1; ++n) {
        const float4* f4 = reinterpret_cast<const float4*>(feats + (size_t)n * CIN_);
        // 4 partial accumulators to break the FMA dependency chain
        float a0 = 0.f, a1 = 0.f, a2 = 0.f, a3 = 0.f;
#pragma unroll
        for (int q = 0; q < 16; ++q) {
            const float4 f = f4[q];               // wave-uniform broadcast load
            a0 += w[q].x * f.x;
            a1 += w[q].y * f.y;
            a2 += w[q].z * f.z;
            a3 += w[q].w * f.w;
        }
        const float acc = (a0 + a1) + (a2 + a3);
        const long row = (long)idxp[n];           // wave-uniform
        atomicAdd(out + row * COUT_ + lane, acc); // contiguous 256B per wave
    }
}

extern "C" void kernel_launch(void* const* d_in, const int* in_sizes, int n_in,
                              void* d_out, int out_size, void* d_ws, size_t ws_size,
                              hipStream_t stream) {
    const float* feats     = (const float*)d_in[0];
    const float* weight    = (const float*)d_in[1];
    const float* bias      = (const float*)d_in[2];
    const int*   out_index = (const int*)d_in[3];
    float* out = (float*)d_out;

    // 1) fill all rows with bias (output buffer is poisoned before each call)
    bias_init_kernel<<<2048, 256, 0, stream>>>(bias, out);

    // 2) scatter-GEMM with atomics
    const int nblocks = (NWAVES + 3) / 4;         // 4 waves per block
    scatter_gemm_kernel<<<nblocks, 256, 0, stream>>>(feats, weight, out_index, out);
}

// Round 3
// 1325.464 us; speedup vs baseline: 1.3920x; 1.3920x over previous
//
#include <hip/hip_runtime.h>

// Sparse ConvTranspose3d scatter-GEMM for MI355X (gfx950) — winner/loser scheme.
// feats: (N, 64) f32; weight: (27, 64, 64) f32; bias: (64,) f32;
// out_index: (27, N) i32; out: (N*27, 64) f32.
//
// R1 showed the all-atomic path is bound by device-scope fp32 atomic RMW
// throughput (~72G dword-atomics/s), everything else idle. out_index rows have
// ~1.08 contributors on average, so:
//   init:    winner[r] = -1                      (tiny kernel, 1.62M ints)
//   claim:   winner[row] = pack(k,n)             (racing plain stores; benign)
//   winners: plain full-line store out[row] = bias + contrib   (~92% of pairs)
//   bias:    rows with winner==-1 get bias only
//   losers:  recompute + atomicAdd               (~8% of pairs)

constexpr int NPTS   = 60000;
constexpr int CIN_   = 64;
constexpr int COUT_  = 64;
constexpr int KV_    = 27;
constexpr long NOUT  = (long)NPTS * KV_;          // 1,620,000 rows
constexpr int PB     = 64;                        // points per wave batch
constexpr int NCHUNK = (NPTS + PB - 1) / PB;      // 938
constexpr int NWAVES = KV_ * NCHUNK;              // 25,326
constexpr int WPB    = 4;                         // waves per block

// ---------------------------------------------------------------------------
// winner[r] = -1 for all rows (d_ws is poisoned 0xAA before every call).
// ---------------------------------------------------------------------------
__global__ __launch_bounds__(256) void winner_init_kernel(int* __restrict__ winner) {
    const long r = (long)blockIdx.x * 256 + threadIdx.x;
    if (r < NOUT) winner[r] = -1;
}

// ---------------------------------------------------------------------------
// claim: winner[out_index[k][n]] = pack(k,n). Races are benign: any surviving
// value is a valid claimant for that row; word stores are atomic at HW level.
// ---------------------------------------------------------------------------
__global__ __launch_bounds__(256) void claim_kernel(const int* __restrict__ out_index,
                                                    int* __restrict__ winner) {
    const int n = blockIdx.x * 256 + threadIdx.x;
    const int k = blockIdx.y;
    if (n < NPTS) {
        const int row = out_index[(size_t)k * NPTS + n];
        winner[row] = (k << 16) | n;
    }
}

// ---------------------------------------------------------------------------
// bias rows: any row nobody claimed gets pure bias.
// ---------------------------------------------------------------------------
__global__ __launch_bounds__(256) void bias_rows_kernel(const float* __restrict__ bias,
                                                        const int* __restrict__ winner,
                                                        float* __restrict__ out) {
    const long r = (long)blockIdx.x * 256 + threadIdx.x;
    if (r >= NOUT) return;
    if (winner[r] == -1) {
        float4* o = reinterpret_cast<float4*>(out + r * COUT_);
        const float4* b4 = reinterpret_cast<const float4*>(bias);
#pragma unroll
        for (int q = 0; q < 16; ++q) o[q] = b4[q];
    }
}

// ---------------------------------------------------------------------------
// main pass. Wave owns (k, 64-point batch). Lane-parallel claim check via
// ballot, then serial loop over selected pairs: broadcast feats row, 64-wide
// dot against the wave-resident weight row, then either a plain full-line
// store (winner phase, bias folded in) or an atomicAdd (loser phase).
// ---------------------------------------------------------------------------
template <bool WINNER_PHASE>
__global__ __launch_bounds__(256) void conv_kernel(const float* __restrict__ feats,
                                                   const float* __restrict__ weight,
                                                   const float* __restrict__ bias,
                                                   const int* __restrict__ out_index,
                                                   const int* __restrict__ winner,
                                                   float* __restrict__ out) {
    const int wave = blockIdx.x * WPB + (threadIdx.x >> 6);
    if (wave >= NWAVES) return;
    const int lane  = threadIdx.x & 63;
    const int k     = wave / NCHUNK;
    const int chunk = wave - k * NCHUNK;
    const int n0 = chunk * PB;

    const int  n     = n0 + lane;
    const bool valid = (n < NPTS);
    const int  idx   = valid ? out_index[(size_t)k * NPTS + n] : -1;
    const int  win   = valid ? winner[idx] : -2;
    const int  pack  = (k << 16) | n;
    const bool mine  = valid && (win == pack);
    unsigned long long mask = __ballot(WINNER_PHASE ? mine : (valid && !mine));
    if (mask == 0ull) return;

    // weight row for this wave's k: 64 VGPRs, reused across all pairs
    const float4* wrow = reinterpret_cast<const float4*>(
        weight + ((size_t)k * COUT_ + lane) * CIN_);
    float4 w[16];
#pragma unroll
    for (int q = 0; q < 16; ++q) w[q] = wrow[q];
    float bv = 0.f;
    if (WINNER_PHASE) bv = bias[lane];

    while (mask) {
        const int b = __ffsll(mask) - 1;
        mask &= mask - 1;
        const int nb = n0 + b;
        const float4* f4 = reinterpret_cast<const float4*>(feats + (size_t)nb * CIN_);
        float a0 = 0.f, a1 = 0.f, a2 = 0.f, a3 = 0.f;
#pragma unroll
        for (int q = 0; q < 16; ++q) {
            const float4 f = f4[q];               // wave-uniform broadcast load
            a0 += w[q].x * f.x;
            a1 += w[q].y * f.y;
            a2 += w[q].z * f.z;
            a3 += w[q].w * f.w;
        }
        const float acc = (a0 + a1) + (a2 + a3);
        const long row = __shfl(idx, b);          // broadcast row id from lane b
        if (WINNER_PHASE) {
            out[row * COUT_ + lane] = bv + acc;   // full 256B line store, no RMW
        } else {
            atomicAdd(out + row * COUT_ + lane, acc);
        }
    }
}

// ---------------------------------------------------------------------------
// Fallback path (ws too small): R1's bias-init + all-atomic scatter.
// ---------------------------------------------------------------------------
__global__ __launch_bounds__(256) void bias_init_kernel(const float* __restrict__ bias,
                                                        float* __restrict__ out) {
    __shared__ float4 b4[16];
    if (threadIdx.x < 16) b4[threadIdx.x] = reinterpret_cast<const float4*>(bias)[threadIdx.x];
    __syncthreads();
    const long total4 = NOUT * (COUT_ / 4);
    long i = (long)blockIdx.x * blockDim.x + threadIdx.x;
    const long stride = (long)gridDim.x * blockDim.x;
    float4* out4 = reinterpret_cast<float4*>(out);
    for (; i < total4; i += stride) out4[i] = b4[i & 15];
}

__global__ __launch_bounds__(256) void scatter_gemm_kernel(const float* __restrict__ feats,
                                                           const float* __restrict__ weight,
                                                           const int* __restrict__ out_index,
                                                           float* __restrict__ out) {
    const int wave = (blockIdx.x << 2) | (threadIdx.x >> 6);
    const int nchunk128 = (NPTS + 127) / 128;
    if (wave >= KV_ * nchunk128) return;
    const int lane  = threadIdx.x & 63;
    const int k     = wave / nchunk128;
    const int chunk = wave - k * nchunk128;
    const int n0 = chunk * 128;
    const int n1 = (n0 + 128 < NPTS) ? (n0 + 128) : NPTS;
    const float4* wrow = reinterpret_cast<const float4*>(
        weight + ((size_t)k * COUT_ + lane) * CIN_);
    float4 w[16];
#pragma unroll
    for (int q = 0; q < 16; ++q) w[q] = wrow[q];
    const int* __restrict__ idxp = out_index + (size_t)k * NPTS;
    for (int n = n0; n < n1; ++n) {
        const float4* f4 = reinterpret_cast<const float4*>(feats + (size_t)n * CIN_);
        float a0 = 0.f, a1 = 0.f, a2 = 0.f, a3 = 0.f;
#pragma unroll
        for (int q = 0; q < 16; ++q) {
            const float4 f = f4[q];
            a0 += w[q].x * f.x; a1 += w[q].y * f.y;
            a2 += w[q].z * f.z; a3 += w[q].w * f.w;
        }
        const float acc = (a0 + a1) + (a2 + a3);
        const long row = (long)idxp[n];
        atomicAdd(out + row * COUT_ + lane, acc);
    }
}

extern "C" void kernel_launch(void* const* d_in, const int* in_sizes, int n_in,
                              void* d_out, int out_size, void* d_ws, size_t ws_size,
                              hipStream_t stream) {
    const float* feats     = (const float*)d_in[0];
    const float* weight    = (const float*)d_in[1];
    const float* bias      = (const float*)d_in[2];
    const int*   out_index = (const int*)d_in[3];
    float* out = (float*)d_out;

    const size_t winner_bytes = (size_t)NOUT * sizeof(int);
    if (ws_size >= winner_bytes) {
        int* winner = (int*)d_ws;
        // 1) winner = -1 everywhere
        winner_init_kernel<<<(int)((NOUT + 255) / 256), 256, 0, stream>>>(winner);
        // 2) claim
        claim_kernel<<<dim3((NPTS + 255) / 256, KV_), 256, 0, stream>>>(out_index, winner);
        // 3) winners: plain stores of bias + contrib
        const int nblocks = (NWAVES + WPB - 1) / WPB;
        conv_kernel<true><<<nblocks, 256, 0, stream>>>(feats, weight, bias, out_index,
                                                       winner, out);
        // 4) unclaimed rows get bias
        bias_rows_kernel<<<(int)((NOUT + 255) / 256), 256, 0, stream>>>(bias, winner, out);
        // 5) losers: recompute + atomicAdd (runs after winners by stream order)
        conv_kernel<false><<<nblocks, 256, 0, stream>>>(feats, weight, bias, out_index,
                                                        winner, out);
    } else {
        // Fallback: R1 path
        bias_init_kernel<<<2048, 256, 0, stream>>>(bias, out);
        const int nblocks = (KV_ * ((NPTS + 127) / 128) + 3) / 4;
        scatter_gemm_kernel<<<nblocks, 256, 0, stream>>>(feats, weight, out_index, out);
    }
}